// Round 3
// baseline (747.872 us; speedup 1.0000x reference)
//
#include <hip/hip_runtime.h>
#include <stdint.h>

#define N_NODES 100000
#define DIM 64
#define RPB 64                                   // rows per bucket
#define NB ((N_NODES + RPB - 1) / RPB)           // 1563 buckets
#define NBLK 128                                 // partition blocks (chunks of edges)
#define TPB_PART 512
#define TPB_AGG 256
#define HIST_LEN (NB * NBLK)                     // 200064
#define SCAN_CHUNK 1024
#define NCH ((HIST_LEN + SCAN_CHUNK - 1) / SCAN_CHUNK)   // 196

// ---------------- fallback: plain atomic scatter ----------------
__global__ void spmm_atomic_kernel(const int* __restrict__ row,
                                   const int* __restrict__ col,
                                   const float* __restrict__ A,
                                   const float* __restrict__ X,
                                   float* __restrict__ out, int E) {
    const long long tid = (long long)blockIdx.x * blockDim.x + threadIdx.x;
    const int e  = (int)(tid >> 4);
    const int f4 = (int)(tid & 15);
    if (e >= E) return;
    const int r = row[e], c = col[e];
    const float a = A[e];
    const float4 x = *reinterpret_cast<const float4*>(X + (size_t)c * DIM + (size_t)f4 * 4);
    float* o = out + (size_t)r * DIM + (size_t)f4 * 4;
    atomicAdd(o + 0, a * x.x);
    atomicAdd(o + 1, a * x.y);
    atomicAdd(o + 2, a * x.z);
    atomicAdd(o + 3, a * x.w);
}

// ---------------- 1) per-block bucket histogram ----------------
// T[bucket * NBLK + block] = #edges of `bucket` in block's chunk (bucket-major for the scan)
__global__ void hist_part(const int* __restrict__ row, int* __restrict__ T, int E) {
    __shared__ int h[NB];
    for (int i = threadIdx.x; i < NB; i += TPB_PART) h[i] = 0;
    __syncthreads();
    const int chunk = (E + NBLK - 1) / NBLK;
    const int s = blockIdx.x * chunk;
    const int e = min(E, s + chunk);
    for (int i = s + threadIdx.x; i < e; i += TPB_PART)
        atomicAdd(&h[row[i] >> 6], 1);
    __syncthreads();
    for (int i = threadIdx.x; i < NB; i += TPB_PART)
        T[i * NBLK + blockIdx.x] = h[i];
}

// ---------------- 2) exclusive scan of T (HIST_LEN elements) ----------------
__global__ void chunk_sum(const int* __restrict__ T, int* __restrict__ csum) {
    __shared__ int lds[256];
    const int base = blockIdx.x * SCAN_CHUNK;
    const int t = threadIdx.x;
    int s = 0;
    for (int i = t; i < SCAN_CHUNK; i += 256) {
        const int gi = base + i;
        s += (gi < HIST_LEN) ? T[gi] : 0;
    }
    lds[t] = s;
    __syncthreads();
    for (int off = 128; off > 0; off >>= 1) {
        if (t < off) lds[t] += lds[t + off];
        __syncthreads();
    }
    if (t == 0) csum[blockIdx.x] = lds[0];
}

__global__ void scan_chunks(int* __restrict__ csum) {   // single block, 256 threads
    __shared__ int lds[256];
    const int t = threadIdx.x;
    const int v = (t < NCH) ? csum[t] : 0;
    lds[t] = v;
    __syncthreads();
    for (int off = 1; off < 256; off <<= 1) {
        const int add = (t >= off) ? lds[t - off] : 0;
        __syncthreads();
        lds[t] += add;
        __syncthreads();
    }
    if (t < NCH) csum[t] = lds[t] - v;                   // exclusive
}

__global__ void local_scan(int* __restrict__ T, const int* __restrict__ csum) {
    __shared__ int lds[256];
    const int base = blockIdx.x * SCAN_CHUNK;
    const int t = threadIdx.x;
    const int gi0 = base + t * 4;
    const int c0 = (gi0 + 0 < HIST_LEN) ? T[gi0 + 0] : 0;
    const int c1 = (gi0 + 1 < HIST_LEN) ? T[gi0 + 1] : 0;
    const int c2 = (gi0 + 2 < HIST_LEN) ? T[gi0 + 2] : 0;
    const int c3 = (gi0 + 3 < HIST_LEN) ? T[gi0 + 3] : 0;
    const int ts = c0 + c1 + c2 + c3;
    lds[t] = ts;
    __syncthreads();
    for (int o = 1; o < 256; o <<= 1) {
        const int a = (t >= o) ? lds[t - o] : 0;
        __syncthreads();
        lds[t] += a;
        __syncthreads();
    }
    const int e0 = lds[t] - ts + csum[blockIdx.x];
    if (gi0 + 0 < HIST_LEN) T[gi0 + 0] = e0;
    if (gi0 + 1 < HIST_LEN) T[gi0 + 1] = e0 + c0;
    if (gi0 + 2 < HIST_LEN) T[gi0 + 2] = e0 + c0 + c1;
    if (gi0 + 3 < HIST_LEN) T[gi0 + 3] = e0 + c0 + c1 + c2;
}

// ---------------- 3) partition scatter (line-clustered writes) ----------------
// rec[pos] = ( row_local<<17 | col , bits(A) )
__global__ void scatter_part(const int* __restrict__ row, const int* __restrict__ col,
                             const float* __restrict__ A, const int* __restrict__ T,
                             int2* __restrict__ rec, int E) {
    __shared__ int base[NB];
    for (int i = threadIdx.x; i < NB; i += TPB_PART)
        base[i] = T[i * NBLK + blockIdx.x];
    __syncthreads();
    const int chunk = (E + NBLK - 1) / NBLK;
    const int s = blockIdx.x * chunk;
    const int e = min(E, s + chunk);
    for (int i = s + threadIdx.x; i < e; i += TPB_PART) {
        const int r = row[i];
        const int b = r >> 6;
        const int pos = atomicAdd(&base[b], 1);
        rec[pos] = make_int2(((r & 63) << 17) | col[i], __float_as_int(A[i]));
    }
}

// ---------------- 4) aggregate: block per bucket, LDS fp32 accumulator ----------------
__global__ void aggregate_lds(const int* __restrict__ T, const int2* __restrict__ rec,
                              const float* __restrict__ X, float* __restrict__ out, int E) {
    __shared__ float acc[RPB * DIM];                    // 16 KB
    const int b = blockIdx.x;
    const int t = threadIdx.x;
    for (int i = t; i < RPB * DIM; i += TPB_AGG) acc[i] = 0.f;
    __syncthreads();

    const int s = T[b * NBLK];
    const int e = (b + 1 < NB) ? T[(b + 1) * NBLK] : E;
    const int wave = t >> 6;
    const int lane = t & 63;
    const int W = TPB_AGG / 64;                          // 4 waves

    int k = s + wave;
    for (; k + W < e; k += 2 * W) {                      // unroll 2 for latency hiding
        const int2 r0 = rec[k];
        const int2 r1 = rec[k + W];
        const float x0 = X[(r0.x & 0x1FFFF) * DIM + lane];
        const float x1 = X[(r1.x & 0x1FFFF) * DIM + lane];
        atomicAdd(&acc[(((unsigned)r0.x) >> 17) * DIM + lane], __int_as_float(r0.y) * x0);
        atomicAdd(&acc[(((unsigned)r1.x) >> 17) * DIM + lane], __int_as_float(r1.y) * x1);
    }
    if (k < e) {
        const int2 r0 = rec[k];
        const float x0 = X[(r0.x & 0x1FFFF) * DIM + lane];
        atomicAdd(&acc[(((unsigned)r0.x) >> 17) * DIM + lane], __int_as_float(r0.y) * x0);
    }
    __syncthreads();

    // coalesced float4 write-out
    const size_t gbase = (size_t)b * RPB * DIM;
    for (int i = t; i < RPB * DIM / 4; i += TPB_AGG) {
        const size_t g = gbase + (size_t)i * 4;
        if (g < (size_t)N_NODES * DIM)
            *reinterpret_cast<float4*>(out + g) = *reinterpret_cast<const float4*>(acc + i * 4);
    }
}

extern "C" void kernel_launch(void* const* d_in, const int* in_sizes, int n_in,
                              void* d_out, int out_size, void* d_ws, size_t ws_size,
                              hipStream_t stream) {
    const int*   edge_index = (const int*)d_in[0];   // [2,E] flat: row then col
    const float* A_vals     = (const float*)d_in[1];
    const float* X          = (const float*)d_in[2];
    float*       out        = (float*)d_out;

    const int E = in_sizes[0] / 2;
    const int* row = edge_index;
    const int* col = edge_index + E;

    // workspace layout
    char* p = (char*)d_ws;
    int* T    = (int*)p;  p += sizeof(int) * (size_t)HIST_LEN;
    int* csum = (int*)p;  p += sizeof(int) * 256;
    p = (char*)(((uintptr_t)p + 15) & ~(uintptr_t)15);
    int2* rec = (int2*)p; p += sizeof(int2) * (size_t)E;
    const size_t needed = (size_t)(p - (char*)d_ws);

    if (ws_size < needed) {
        hipMemsetAsync(out, 0, (size_t)out_size * sizeof(float), stream);
        const long long total = (long long)E * 16;
        spmm_atomic_kernel<<<(int)((total + 255) / 256), 256, 0, stream>>>(row, col, A_vals, X, out, E);
        return;
    }

    hist_part<<<NBLK, TPB_PART, 0, stream>>>(row, T, E);
    chunk_sum<<<NCH, 256, 0, stream>>>(T, csum);
    scan_chunks<<<1, 256, 0, stream>>>(csum);
    local_scan<<<NCH, 256, 0, stream>>>(T, csum);
    scatter_part<<<NBLK, TPB_PART, 0, stream>>>(row, col, A_vals, T, rec, E);
    aggregate_lds<<<NB, TPB_AGG, 0, stream>>>(T, rec, X, out, E);
}